// Round 9
// baseline (200.394 us; speedup 1.0000x reference)
//
#include <hip/hip_runtime.h>
#include <stdint.h>

typedef __attribute__((ext_vector_type(8))) short bf8;   // 8 bf16 = 4 VGPRs
typedef __attribute__((ext_vector_type(4))) float f4;

// ---------------- DPP 64-lane reduction helpers ----------------
template<int CTRL>
__device__ __forceinline__ float dppMove(float v, float ident) {
  return __int_as_float(__builtin_amdgcn_update_dpp(
      __float_as_int(ident), __float_as_int(v), CTRL, 0xf, 0xf, false));
}
__device__ __forceinline__ float waveSum63(float v) {
  v += dppMove<0x128>(v, 0.f);   // row_ror:8
  v += dppMove<0x124>(v, 0.f);   // row_ror:4
  v += dppMove<0x122>(v, 0.f);   // row_ror:2
  v += dppMove<0x121>(v, 0.f);   // row_ror:1
  v += dppMove<0x142>(v, 0.f);   // row_bcast15
  v += dppMove<0x143>(v, 0.f);   // row_bcast31
  return v;                      // lane 63 holds full sum
}
__device__ __forceinline__ float waveMax63(float v) {
  v = fmaxf(v, dppMove<0x128>(v, -3e38f));
  v = fmaxf(v, dppMove<0x124>(v, -3e38f));
  v = fmaxf(v, dppMove<0x122>(v, -3e38f));
  v = fmaxf(v, dppMove<0x121>(v, -3e38f));
  v = fmaxf(v, dppMove<0x142>(v, -3e38f));
  v = fmaxf(v, dppMove<0x143>(v, -3e38f));
  return v;
}
__device__ __forceinline__ float bcast63(float v) {
  return __int_as_float(__builtin_amdgcn_readlane(__float_as_int(v), 63));
}
__device__ __forceinline__ ushort f2bf(float f) {
  uint32_t b = __float_as_uint(f);
  uint32_t r = (b + 0x7fffu + ((b >> 16) & 1u)) >> 16;
  return (ushort)r;
}
__device__ __forceinline__ float bf2f(ushort u) {
  return __uint_as_float(((uint32_t)u) << 16);
}

// ---------------- prologue: center cast + weight casts + kA, one launch ------
// blocks [0,2048): cast center (f32->bf16)
// blocks [2048,2304): cast Wout & Wgate
// blocks [2304,2816): Mtb[n][d] = sum_e Wq[h][e][d]*Wk[h][e][dk], n=h*256+dk
__global__ __launch_bounds__(256)
void mhna_prologue(const float* __restrict__ center, ushort* __restrict__ centerBf,
                   const float* __restrict__ Wout, const float* __restrict__ Wgate,
                   ushort* __restrict__ Woutb, ushort* __restrict__ Wgb,
                   const float* __restrict__ Wq, const float* __restrict__ Wk,
                   ushort* __restrict__ Mtb) {
  const int blk = blockIdx.x;
  const int t = threadIdx.x;
  if (blk < 2048) {
    const int n4 = 16384 * 256 / 4;
    int i = blk * 256 + t;
    for (; i < n4; i += 2048 * 256) {
      float4 v = ((const float4*)center)[i];
      ushort4 u;
      u.x = f2bf(v.x); u.y = f2bf(v.y); u.z = f2bf(v.z); u.w = f2bf(v.w);
      ((ushort4*)centerBf)[i] = u;
    }
  } else if (blk < 2304) {
    const int n4 = 256 * 512 / 4;
    int i = (blk - 2048) * 256 + t;      // 0..65535 covers both matrices
    const float* s = (i < n4) ? Wout : Wgate;
    ushort* d = (i < n4) ? Woutb : Wgb;
    int j = (i < n4) ? i : i - n4;
    float4 v = ((const float4*)s)[j];
    ushort4 u;
    u.x = f2bf(v.x); u.y = f2bf(v.y); u.z = f2bf(v.z); u.w = f2bf(v.w);
    ((ushort4*)d)[j] = u;
  } else {
    const int n = blk - 2304;            // 0..511
    const int h = n >> 8, dk = n & 255;
    // 4 independent FMA chains (dependent-FMA latency ~4cyc -> 3x faster)
    float a0 = 0.f, a1 = 0.f, a2 = 0.f, a3 = 0.f;
#pragma unroll 4
    for (int e = 0; e < 128; e += 4) {
      a0 = fmaf(Wq[(size_t)(h * 128 + e + 0) * 256 + t],
                Wk[(size_t)(h * 128 + e + 0) * 256 + dk], a0);
      a1 = fmaf(Wq[(size_t)(h * 128 + e + 1) * 256 + t],
                Wk[(size_t)(h * 128 + e + 1) * 256 + dk], a1);
      a2 = fmaf(Wq[(size_t)(h * 128 + e + 2) * 256 + t],
                Wk[(size_t)(h * 128 + e + 2) * 256 + dk], a2);
      a3 = fmaf(Wq[(size_t)(h * 128 + e + 3) * 256 + t],
                Wk[(size_t)(h * 128 + e + 3) * 256 + dk], a3);
    }
    Mtb[(size_t)n * 256 + t] = f2bf((a0 + a1) + (a2 + a3));
  }
}

// ---------------- qM GEMM: qMb[16384][512] = centerBf @ Mtb^T (bf16 out)
// block = 64 rows x 256 cols (col-split), 8 waves; grid 512 (2 blocks/CU).
// Col-split halves the weight panel per block (128KB) WITHOUT re-reading it
// (total panel traffic unchanged -- unlike the R7 row-split regression).
__global__ __launch_bounds__(512)
void gemm_qM(const ushort* __restrict__ A, const ushort* __restrict__ W,
             ushort* __restrict__ Cb) {
  const int t = threadIdx.x;
  const int w = t >> 6, l = t & 63;
  const int row0 = (blockIdx.x >> 1) * 64;
  const int col0 = (blockIdx.x & 1) * 256 + w * 32;
  const int lr = l & 15, lg = l >> 4;

  f4 acc[4][2];
#pragma unroll
  for (int i = 0; i < 4; ++i)
#pragma unroll
    for (int j = 0; j < 2; ++j) acc[i][j] = (f4)0.f;

#pragma unroll 2
  for (int kk = 0; kk < 256; kk += 32) {
    bf8 af[4];
#pragma unroll
    for (int i = 0; i < 4; ++i)
      af[i] = *(const bf8*)(A + (size_t)(row0 + i * 16 + lr) * 256 + kk + lg * 8);
#pragma unroll
    for (int j = 0; j < 2; ++j) {
      bf8 bw = *(const bf8*)(W + (size_t)(col0 + j * 16 + lr) * 256 + kk + lg * 8);
#pragma unroll
      for (int i = 0; i < 4; ++i)
        acc[i][j] = __builtin_amdgcn_mfma_f32_16x16x32_bf16(af[i], bw, acc[i][j], 0, 0, 0);
    }
  }
#pragma unroll
  for (int i = 0; i < 4; ++i)
#pragma unroll
    for (int j = 0; j < 2; ++j)
#pragma unroll
      for (int r = 0; r < 4; ++r)
        Cb[(size_t)(row0 + i * 16 + lg * 4 + r) * 512 + col0 + j * 16 + lr] =
            f2bf(acc[i][j][r]);
}

// ---------------- kC v2: fused scores/softmax/ctx, MASK-SKIPPED loads --------
// masked neighbors have attn == exactly 0 (expf(-1e9-mx) underflows) -> their
// rows are never needed; skip the 1KB row load entirely (wave-uniform branch).
__global__ __launch_bounds__(256)
void mhna_kC(const float* __restrict__ nbg, const ushort* __restrict__ qMb,
             const float* __restrict__ wts, const int* __restrict__ msk,
             ushort* __restrict__ ctxb) {
  __shared__ float sc_s[2][64];
  __shared__ float at_s[2][64];
  __shared__ float part[4][512];   // per-wave ctx partials [w][h*256+d]
  const int b = blockIdx.x;
  const int t = threadIdx.x;
  const int w = t >> 6, lam = t & 63;

  // lane's mask bit + weight, hoisted to kernel entry (off the softmax path)
  const int mv_l = msk[(size_t)b * 64 + lam];
  const float wv_l = wts[(size_t)b * 64 + lam];
  const unsigned long long mb = __ballot(mv_l != 0);

  // qM (bf16) -> f32: lane owns d-slice [4lam, 4lam+4) per head
  const ushort4* qm4 = (const ushort4*)(qMb + (size_t)b * 512);
  ushort4 ua = qm4[lam];
  ushort4 ub = qm4[64 + lam];
  f4 qa = {bf2f(ua.x), bf2f(ua.y), bf2f(ua.z), bf2f(ua.w)};
  f4 qb = {bf2f(ub.x), bf2f(ub.y), bf2f(ub.z), bf2f(ub.w)};

  const float4* nb4 = (const float4*)(nbg + (size_t)b * (64 * 256));
  float4 st[16];                     // wave w holds rows k = r*4+w
#pragma unroll
  for (int r = 0; r < 16; ++r) {
    st[r] = make_float4(0.f, 0.f, 0.f, 0.f);
    const int k = r * 4 + w;
    if ((mb >> k) & 1ull) st[r] = nb4[k * 64 + lam];
  }

  // scores: per-lane partial dot + 64-lane DPP reduce (unmasked rows only)
#pragma unroll
  for (int r = 0; r < 16; ++r) {
    const int k = r * 4 + w;
    if ((mb >> k) & 1ull) {
      float4 v = st[r];
      float p0 = v.x * qa.x + v.y * qa.y + v.z * qa.z + v.w * qa.w;
      float p1 = v.x * qb.x + v.y * qb.y + v.z * qb.z + v.w * qb.w;
      float s0 = waveSum63(p0);
      float s1 = waveSum63(p1);
      if (lam == 63) { sc_s[0][k] = s0; sc_s[1][k] = s1; }
    }
  }
  __syncthreads();

  // softmax: wave 0 -> h=0, wave 1 -> h=1 (k = lam)
  if (t < 128) {
    const int h = w;
    float s = sc_s[h][lam];          // garbage if masked -> selected away
    s = mv_l ? fmaf(s, 0.08838834764831845f, wv_l) : -1e9f;
    float mx = bcast63(waveMax63(s));
    float e = __expf(s - mx);
    float sm = bcast63(waveSum63(e));
    at_s[h][lam] = e / sm;
  }
  __syncthreads();

  // ctx partials from registers: lane owns d-slice [4lam,4lam+4), k = r*4+w
  float c0[4] = {0.f, 0.f, 0.f, 0.f};
  float c1[4] = {0.f, 0.f, 0.f, 0.f};
#pragma unroll
  for (int r = 0; r < 16; ++r) {
    const int k = r * 4 + w;
    if ((mb >> k) & 1ull) {
      const float A0 = at_s[0][k];   // uniform addr -> LDS broadcast
      const float A1 = at_s[1][k];
      float4 v = st[r];
      c0[0] = fmaf(A0, v.x, c0[0]); c0[1] = fmaf(A0, v.y, c0[1]);
      c0[2] = fmaf(A0, v.z, c0[2]); c0[3] = fmaf(A0, v.w, c0[3]);
      c1[0] = fmaf(A1, v.x, c1[0]); c1[1] = fmaf(A1, v.y, c1[1]);
      c1[2] = fmaf(A1, v.z, c1[2]); c1[3] = fmaf(A1, v.w, c1[3]);
    }
  }
  f4 p0v = {c0[0], c0[1], c0[2], c0[3]};
  f4 p1v = {c1[0], c1[1], c1[2], c1[3]};
  *(f4*)&part[w][lam * 4]       = p0v;
  *(f4*)&part[w][256 + lam * 4] = p1v;
  __syncthreads();

  // cross-wave reduce + bf16 store: thread t owns feature d = t for both heads
  float r0 = part[0][t] + part[1][t] + part[2][t] + part[3][t];
  float r1 = part[0][256 + t] + part[1][256 + t] + part[2][256 + t] + part[3][256 + t];
  ctxb[(size_t)b * 512 + t] = f2bf(r0);
  ctxb[(size_t)b * 512 + 256 + t] = f2bf(r1);
}

// ---------------- PG: fused P-GEMM + gate-GEMM + sigmoid blend ----------------
// block = 64 rows x 256 cols, 8 waves (wave w: cols [32w,32w+32)); grid 256.
// P kept in LDS as bf16 (MFMA A-fragments for pass B, direct bf8 reads) and
// in acc1 registers (f32) for the blend epilogue -- no f32 LDS round trip.
#define LDPB 264   // ushort stride: row = 528B; 16B-aligned; 2-way bank pattern
__global__ __launch_bounds__(512)
void mhna_PG(const ushort* __restrict__ ctxb, const ushort* __restrict__ Woutb,
             const ushort* __restrict__ centerBf, const ushort* __restrict__ Wgb,
             float* __restrict__ out) {
  __shared__ ushort p_s[64][LDPB];
  const int t = threadIdx.x;
  const int w = t >> 6, l = t & 63;
  const int row0 = blockIdx.x * 64;
  const int col0 = w * 32;
  const int lr = l & 15, lg = l >> 4;

  // ---- phase 1: P = multi_ctx @ Wout^T (K=512) ----
  f4 acc1[4][2];
#pragma unroll
  for (int i = 0; i < 4; ++i)
#pragma unroll
    for (int j = 0; j < 2; ++j) acc1[i][j] = (f4)0.f;

#pragma unroll 2
  for (int kk = 0; kk < 512; kk += 32) {
    bf8 af[4];
#pragma unroll
    for (int i = 0; i < 4; ++i)
      af[i] = *(const bf8*)(ctxb + (size_t)(row0 + i * 16 + lr) * 512 + kk + lg * 8);
#pragma unroll
    for (int j = 0; j < 2; ++j) {
      bf8 bw = *(const bf8*)(Woutb + (size_t)(col0 + j * 16 + lr) * 512 + kk + lg * 8);
#pragma unroll
      for (int i = 0; i < 4; ++i)
        acc1[i][j] = __builtin_amdgcn_mfma_f32_16x16x32_bf16(af[i], bw, acc1[i][j], 0, 0, 0);
    }
  }
#pragma unroll
  for (int i = 0; i < 4; ++i)
#pragma unroll
    for (int j = 0; j < 2; ++j)
#pragma unroll
      for (int r = 0; r < 4; ++r)
        p_s[i * 16 + lg * 4 + r][col0 + j * 16 + lr] = f2bf(acc1[i][j][r]);
  __syncthreads();

  // ---- phase 2: gate = center @ Wg1^T + P @ Wg2^T ----
  f4 acc2[4][2];
#pragma unroll
  for (int i = 0; i < 4; ++i)
#pragma unroll
    for (int j = 0; j < 2; ++j) acc2[i][j] = (f4)0.f;

  // pass A: center (bf16 from global), Wg cols [0,256)
#pragma unroll 2
  for (int kk = 0; kk < 256; kk += 32) {
    bf8 af[4];
#pragma unroll
    for (int i = 0; i < 4; ++i)
      af[i] = *(const bf8*)(centerBf + (size_t)(row0 + i * 16 + lr) * 256 + kk + lg * 8);
#pragma unroll
    for (int j = 0; j < 2; ++j) {
      bf8 bw = *(const bf8*)(Wgb + (size_t)(col0 + j * 16 + lr) * 512 + kk + lg * 8);
#pragma unroll
      for (int i = 0; i < 4; ++i)
        acc2[i][j] = __builtin_amdgcn_mfma_f32_16x16x32_bf16(af[i], bw, acc2[i][j], 0, 0, 0);
    }
  }
  // pass B: P (bf16 direct from LDS), Wg cols [256,512)
#pragma unroll 2
  for (int kk = 0; kk < 256; kk += 32) {
    bf8 af[4];
#pragma unroll
    for (int i = 0; i < 4; ++i)
      af[i] = *(const bf8*)&p_s[i * 16 + lr][kk + lg * 8];
#pragma unroll
    for (int j = 0; j < 2; ++j) {
      bf8 bw = *(const bf8*)(Wgb + (size_t)(col0 + j * 16 + lr) * 512 + 256 + kk + lg * 8);
#pragma unroll
      for (int i = 0; i < 4; ++i)
        acc2[i][j] = __builtin_amdgcn_mfma_f32_16x16x32_bf16(af[i], bw, acc2[i][j], 0, 0, 0);
    }
  }

  // ---- epilogue: gate blend (P f32 from registers, center bf16) ----
#pragma unroll
  for (int i = 0; i < 4; ++i)
#pragma unroll
    for (int j = 0; j < 2; ++j)
#pragma unroll
      for (int r = 0; r < 4; ++r) {
        const int row = row0 + i * 16 + lg * 4 + r;
        const int col = col0 + j * 16 + lr;
        float g = 1.f / (1.f + __expf(-acc2[i][j][r]));
        float pv = acc1[i][j][r];
        float cv = bf2f(centerBf[(size_t)row * 256 + col]);
        out[(size_t)row * 256 + col] = g * cv + (1.f - g) * pv;
      }
}

extern "C" void kernel_launch(void* const* d_in, const int* in_sizes, int n_in,
                              void* d_out, int out_size, void* d_ws, size_t ws_size,
                              hipStream_t stream) {
  const float* center = (const float*)d_in[0];
  const float* neigh  = (const float*)d_in[1];
  const float* nw     = (const float*)d_in[2];
  const int*   nm     = (const int*)d_in[3];
  const float* Wq     = (const float*)d_in[4];
  const float* Wk     = (const float*)d_in[5];
  const float* Wout   = (const float*)d_in[6];
  const float* Wgate  = (const float*)d_in[7];
  float* out = (float*)d_out;

  char* ws = (char*)d_ws;
  size_t off = 0;
  ushort* Mtb      = (ushort*)(ws + off); off += (size_t)512 * 256 * 2;        // 256 KB
  ushort* centerBf = (ushort*)(ws + off); off += (size_t)16384 * 256 * 2;      // 8 MB
  ushort* qMb      = (ushort*)(ws + off); off += (size_t)16384 * 512 * 2;      // 16 MB
  ushort* ctxb     = (ushort*)(ws + off); off += (size_t)16384 * 512 * 2;      // 16 MB
  ushort* Woutb    = (ushort*)(ws + off); off += (size_t)256 * 512 * 2;        // 256 KB
  ushort* Wgb      = (ushort*)(ws + off); off += (size_t)256 * 512 * 2;        // 256 KB

  // prologue: center cast + weight casts + Mt = Wq^T Wk (one launch)
  mhna_prologue<<<2816, 256, 0, stream>>>(center, centerBf, Wout, Wgate,
                                          Woutb, Wgb, Wq, Wk, Mtb);
  // qM = center @ Mt^T : [16384 x 512] bf16, K=256 (col-split, 2 blocks/CU)
  gemm_qM<<<512, 512, 0, stream>>>(centerBf, Mtb, qMb);
  // fused neighborhood attention (register-resident, mask-skipped loads)
  mhna_kC<<<16384, 256, 0, stream>>>(neigh, qMb, nw, nm, ctxb);
  // fused: P = ctx @ Wout^T ; gate = sigmoid([center,P] @ Wg^T) ; blend
  mhna_PG<<<256, 512, 0, stream>>>(ctxb, Woutb, centerBf, Wgb, out);
}

// Round 10
// 194.772 us; speedup vs baseline: 1.0289x; 1.0289x over previous
//
#include <hip/hip_runtime.h>
#include <stdint.h>

typedef __attribute__((ext_vector_type(8))) short bf8;   // 8 bf16 = 4 VGPRs
typedef __attribute__((ext_vector_type(4))) float f4;

// ---------------- DPP 64-lane reduction helpers ----------------
template<int CTRL>
__device__ __forceinline__ float dppMove(float v, float ident) {
  return __int_as_float(__builtin_amdgcn_update_dpp(
      __float_as_int(ident), __float_as_int(v), CTRL, 0xf, 0xf, false));
}
__device__ __forceinline__ float waveSum63(float v) {
  v += dppMove<0x128>(v, 0.f);   // row_ror:8
  v += dppMove<0x124>(v, 0.f);   // row_ror:4
  v += dppMove<0x122>(v, 0.f);   // row_ror:2
  v += dppMove<0x121>(v, 0.f);   // row_ror:1
  v += dppMove<0x142>(v, 0.f);   // row_bcast15
  v += dppMove<0x143>(v, 0.f);   // row_bcast31
  return v;                      // lane 63 holds full sum
}
__device__ __forceinline__ float waveMax63(float v) {
  v = fmaxf(v, dppMove<0x128>(v, -3e38f));
  v = fmaxf(v, dppMove<0x124>(v, -3e38f));
  v = fmaxf(v, dppMove<0x122>(v, -3e38f));
  v = fmaxf(v, dppMove<0x121>(v, -3e38f));
  v = fmaxf(v, dppMove<0x142>(v, -3e38f));
  v = fmaxf(v, dppMove<0x143>(v, -3e38f));
  return v;
}
__device__ __forceinline__ float bcast63(float v) {
  return __int_as_float(__builtin_amdgcn_readlane(__float_as_int(v), 63));
}
__device__ __forceinline__ ushort f2bf(float f) {
  uint32_t b = __float_as_uint(f);
  uint32_t r = (b + 0x7fffu + ((b >> 16) & 1u)) >> 16;
  return (ushort)r;
}
__device__ __forceinline__ float bf2f(ushort u) {
  return __uint_as_float(((uint32_t)u) << 16);
}

// ---------------- prologue: center cast + weight casts + kA, one launch ------
// blocks [0,2048): cast center (f32->bf16)
// blocks [2048,2304): cast Wout & Wgate
// blocks [2304,2816): Mtb[n][d] = sum_e Wq[h][e][d]*Wk[h][e][dk], n=h*256+dk
__global__ __launch_bounds__(256)
void mhna_prologue(const float* __restrict__ center, ushort* __restrict__ centerBf,
                   const float* __restrict__ Wout, const float* __restrict__ Wgate,
                   ushort* __restrict__ Woutb, ushort* __restrict__ Wgb,
                   const float* __restrict__ Wq, const float* __restrict__ Wk,
                   ushort* __restrict__ Mtb) {
  const int blk = blockIdx.x;
  const int t = threadIdx.x;
  if (blk < 2048) {
    const int n4 = 16384 * 256 / 4;
    int i = blk * 256 + t;
    for (; i < n4; i += 2048 * 256) {
      float4 v = ((const float4*)center)[i];
      ushort4 u;
      u.x = f2bf(v.x); u.y = f2bf(v.y); u.z = f2bf(v.z); u.w = f2bf(v.w);
      ((ushort4*)centerBf)[i] = u;
    }
  } else if (blk < 2304) {
    const int n4 = 256 * 512 / 4;
    int i = (blk - 2048) * 256 + t;      // 0..65535 covers both matrices
    const float* s = (i < n4) ? Wout : Wgate;
    ushort* d = (i < n4) ? Woutb : Wgb;
    int j = (i < n4) ? i : i - n4;
    float4 v = ((const float4*)s)[j];
    ushort4 u;
    u.x = f2bf(v.x); u.y = f2bf(v.y); u.z = f2bf(v.z); u.w = f2bf(v.w);
    ((ushort4*)d)[j] = u;
  } else {
    const int n = blk - 2304;            // 0..511
    const int h = n >> 8, dk = n & 255;
    // 4 independent FMA chains (dependent-FMA latency ~4cyc -> 3x faster)
    float a0 = 0.f, a1 = 0.f, a2 = 0.f, a3 = 0.f;
#pragma unroll 4
    for (int e = 0; e < 128; e += 4) {
      a0 = fmaf(Wq[(size_t)(h * 128 + e + 0) * 256 + t],
                Wk[(size_t)(h * 128 + e + 0) * 256 + dk], a0);
      a1 = fmaf(Wq[(size_t)(h * 128 + e + 1) * 256 + t],
                Wk[(size_t)(h * 128 + e + 1) * 256 + dk], a1);
      a2 = fmaf(Wq[(size_t)(h * 128 + e + 2) * 256 + t],
                Wk[(size_t)(h * 128 + e + 2) * 256 + dk], a2);
      a3 = fmaf(Wq[(size_t)(h * 128 + e + 3) * 256 + t],
                Wk[(size_t)(h * 128 + e + 3) * 256 + dk], a3);
    }
    Mtb[(size_t)n * 256 + t] = f2bf((a0 + a1) + (a2 + a3));
  }
}

// ---------------- qM GEMM: qMb[16384][512] = centerBf @ Mtb^T (bf16 out)
// block = 64 rows x 512 cols, 8 waves; grid 256. Weight panel (512x256 bf16 =
// 256KB, L2-resident) read ONCE per block; max per-wave MFMA density
// (16 MFMA : 8 loads per K-step). Splits along either axis measured WORSE
// (R7 row-split +16us, R9 col-split +6us) -- latency-bound, not footprint.
__global__ __launch_bounds__(512)
void gemm_qM(const ushort* __restrict__ A, const ushort* __restrict__ W,
             ushort* __restrict__ Cb) {
  const int t = threadIdx.x;
  const int w = t >> 6, l = t & 63;
  const int row0 = blockIdx.x * 64;
  const int col0 = w * 64;
  const int lr = l & 15, lg = l >> 4;

  f4 acc[4][4];
#pragma unroll
  for (int i = 0; i < 4; ++i)
#pragma unroll
    for (int j = 0; j < 4; ++j) acc[i][j] = (f4)0.f;

#pragma unroll 2
  for (int kk = 0; kk < 256; kk += 32) {
    bf8 af[4];
#pragma unroll
    for (int i = 0; i < 4; ++i)
      af[i] = *(const bf8*)(A + (size_t)(row0 + i * 16 + lr) * 256 + kk + lg * 8);
#pragma unroll
    for (int j = 0; j < 4; ++j) {
      bf8 bw = *(const bf8*)(W + (size_t)(col0 + j * 16 + lr) * 256 + kk + lg * 8);
#pragma unroll
      for (int i = 0; i < 4; ++i)
        acc[i][j] = __builtin_amdgcn_mfma_f32_16x16x32_bf16(af[i], bw, acc[i][j], 0, 0, 0);
    }
  }
#pragma unroll
  for (int i = 0; i < 4; ++i)
#pragma unroll
    for (int j = 0; j < 4; ++j)
#pragma unroll
      for (int r = 0; r < 4; ++r)
        Cb[(size_t)(row0 + i * 16 + lg * 4 + r) * 512 + col0 + j * 16 + lr] =
            f2bf(acc[i][j][r]);
}

// ---------------- kC v2: fused scores/softmax/ctx, MASK-SKIPPED loads --------
// masked neighbors have attn == exactly 0 (expf(-1e9-mx) underflows) -> their
// rows are never needed; skip the 1KB row load entirely (wave-uniform branch).
// Load side is optimal: 1 global_load_dwordx4 per 1KB row, 16 rows in flight
// per wave; remaining cost is DRAM row-activation overhead of the 50%-density
// gather (~4-4.5 TB/s effective vs 6.3 dense ceiling).
__global__ __launch_bounds__(256)
void mhna_kC(const float* __restrict__ nbg, const ushort* __restrict__ qMb,
             const float* __restrict__ wts, const int* __restrict__ msk,
             ushort* __restrict__ ctxb) {
  __shared__ float sc_s[2][64];
  __shared__ float at_s[2][64];
  __shared__ float part[4][512];   // per-wave ctx partials [w][h*256+d]
  const int b = blockIdx.x;
  const int t = threadIdx.x;
  const int w = t >> 6, lam = t & 63;

  // lane's mask bit + weight, hoisted to kernel entry (off the softmax path)
  const int mv_l = msk[(size_t)b * 64 + lam];
  const float wv_l = wts[(size_t)b * 64 + lam];
  const unsigned long long mb = __ballot(mv_l != 0);

  // qM (bf16) -> f32: lane owns d-slice [4lam, 4lam+4) per head
  const ushort4* qm4 = (const ushort4*)(qMb + (size_t)b * 512);
  ushort4 ua = qm4[lam];
  ushort4 ub = qm4[64 + lam];
  f4 qa = {bf2f(ua.x), bf2f(ua.y), bf2f(ua.z), bf2f(ua.w)};
  f4 qb = {bf2f(ub.x), bf2f(ub.y), bf2f(ub.z), bf2f(ub.w)};

  const float4* nb4 = (const float4*)(nbg + (size_t)b * (64 * 256));
  float4 st[16];                     // wave w holds rows k = r*4+w
#pragma unroll
  for (int r = 0; r < 16; ++r) {
    st[r] = make_float4(0.f, 0.f, 0.f, 0.f);
    const int k = r * 4 + w;
    if ((mb >> k) & 1ull) st[r] = nb4[k * 64 + lam];
  }

  // scores: per-lane partial dot + 64-lane DPP reduce (unmasked rows only)
#pragma unroll
  for (int r = 0; r < 16; ++r) {
    const int k = r * 4 + w;
    if ((mb >> k) & 1ull) {
      float4 v = st[r];
      float p0 = v.x * qa.x + v.y * qa.y + v.z * qa.z + v.w * qa.w;
      float p1 = v.x * qb.x + v.y * qb.y + v.z * qb.z + v.w * qb.w;
      float s0 = waveSum63(p0);
      float s1 = waveSum63(p1);
      if (lam == 63) { sc_s[0][k] = s0; sc_s[1][k] = s1; }
    }
  }
  __syncthreads();

  // softmax: wave 0 -> h=0, wave 1 -> h=1 (k = lam)
  if (t < 128) {
    const int h = w;
    float s = sc_s[h][lam];          // garbage if masked -> selected away
    s = mv_l ? fmaf(s, 0.08838834764831845f, wv_l) : -1e9f;
    float mx = bcast63(waveMax63(s));
    float e = __expf(s - mx);
    float sm = bcast63(waveSum63(e));
    at_s[h][lam] = e / sm;
  }
  __syncthreads();

  // ctx partials from registers: lane owns d-slice [4lam,4lam+4), k = r*4+w
  float c0[4] = {0.f, 0.f, 0.f, 0.f};
  float c1[4] = {0.f, 0.f, 0.f, 0.f};
#pragma unroll
  for (int r = 0; r < 16; ++r) {
    const int k = r * 4 + w;
    if ((mb >> k) & 1ull) {
      const float A0 = at_s[0][k];   // uniform addr -> LDS broadcast
      const float A1 = at_s[1][k];
      float4 v = st[r];
      c0[0] = fmaf(A0, v.x, c0[0]); c0[1] = fmaf(A0, v.y, c0[1]);
      c0[2] = fmaf(A0, v.z, c0[2]); c0[3] = fmaf(A0, v.w, c0[3]);
      c1[0] = fmaf(A1, v.x, c1[0]); c1[1] = fmaf(A1, v.y, c1[1]);
      c1[2] = fmaf(A1, v.z, c1[2]); c1[3] = fmaf(A1, v.w, c1[3]);
    }
  }
  f4 p0v = {c0[0], c0[1], c0[2], c0[3]};
  f4 p1v = {c1[0], c1[1], c1[2], c1[3]};
  *(f4*)&part[w][lam * 4]       = p0v;
  *(f4*)&part[w][256 + lam * 4] = p1v;
  __syncthreads();

  // cross-wave reduce + bf16 store: thread t owns feature d = t for both heads
  float r0 = part[0][t] + part[1][t] + part[2][t] + part[3][t];
  float r1 = part[0][256 + t] + part[1][256 + t] + part[2][256 + t] + part[3][256 + t];
  ctxb[(size_t)b * 512 + t] = f2bf(r0);
  ctxb[(size_t)b * 512 + 256 + t] = f2bf(r1);
}

// ---------------- PG: fused P-GEMM + gate-GEMM + sigmoid blend ----------------
// block = 64 rows x 256 cols, 8 waves (wave w: cols [32w,32w+32)); grid 256.
// P tile kept in LDS f32 (never touches HBM).
#define LDP 260   // stride%32==4 -> 2-way (free) bank pattern; rows 16B-aligned
__global__ __launch_bounds__(512)
void mhna_PG(const ushort* __restrict__ ctxb, const ushort* __restrict__ Woutb,
             const ushort* __restrict__ centerBf, const ushort* __restrict__ Wgb,
             float* __restrict__ out) {
  __shared__ float p_s[64][LDP];
  const int t = threadIdx.x;
  const int w = t >> 6, l = t & 63;
  const int row0 = blockIdx.x * 64;
  const int col0 = w * 32;
  const int lr = l & 15, lg = l >> 4;

  // ---- phase 1: P = multi_ctx @ Wout^T (K=512) ----
  f4 acc1[4][2];
#pragma unroll
  for (int i = 0; i < 4; ++i)
#pragma unroll
    for (int j = 0; j < 2; ++j) acc1[i][j] = (f4)0.f;

#pragma unroll 2
  for (int kk = 0; kk < 512; kk += 32) {
    bf8 af[4];
#pragma unroll
    for (int i = 0; i < 4; ++i)
      af[i] = *(const bf8*)(ctxb + (size_t)(row0 + i * 16 + lr) * 512 + kk + lg * 8);
#pragma unroll
    for (int j = 0; j < 2; ++j) {
      bf8 bw = *(const bf8*)(Woutb + (size_t)(col0 + j * 16 + lr) * 512 + kk + lg * 8);
#pragma unroll
      for (int i = 0; i < 4; ++i)
        acc1[i][j] = __builtin_amdgcn_mfma_f32_16x16x32_bf16(af[i], bw, acc1[i][j], 0, 0, 0);
    }
  }
#pragma unroll
  for (int i = 0; i < 4; ++i)
#pragma unroll
    for (int j = 0; j < 2; ++j)
#pragma unroll
      for (int r = 0; r < 4; ++r)
        p_s[i * 16 + lg * 4 + r][col0 + j * 16 + lr] = acc1[i][j][r];
  __syncthreads();

  // ---- phase 2: gate = center @ Wg1^T + P @ Wg2^T ----
  f4 acc2[4][2];
#pragma unroll
  for (int i = 0; i < 4; ++i)
#pragma unroll
    for (int j = 0; j < 2; ++j) acc2[i][j] = (f4)0.f;

  // pass A: center (bf16 from global), Wg cols [0,256)
#pragma unroll 2
  for (int kk = 0; kk < 256; kk += 32) {
    bf8 af[4];
#pragma unroll
    for (int i = 0; i < 4; ++i)
      af[i] = *(const bf8*)(centerBf + (size_t)(row0 + i * 16 + lr) * 256 + kk + lg * 8);
#pragma unroll
    for (int j = 0; j < 2; ++j) {
      bf8 bw = *(const bf8*)(Wgb + (size_t)(col0 + j * 16 + lr) * 512 + kk + lg * 8);
#pragma unroll
      for (int i = 0; i < 4; ++i)
        acc2[i][j] = __builtin_amdgcn_mfma_f32_16x16x32_bf16(af[i], bw, acc2[i][j], 0, 0, 0);
    }
  }
  // pass B: P (f32 from LDS -> bf16 fragments), Wg cols [256,512)
#pragma unroll 2
  for (int kk = 0; kk < 256; kk += 32) {
    bf8 af[4];
#pragma unroll
    for (int i = 0; i < 4; ++i) {
      f4 x0 = *(const f4*)&p_s[i * 16 + lr][kk + lg * 8];
      f4 x1 = *(const f4*)&p_s[i * 16 + lr][kk + lg * 8 + 4];
      bf8 a;
      a[0] = (short)f2bf(x0.x); a[1] = (short)f2bf(x0.y);
      a[2] = (short)f2bf(x0.z); a[3] = (short)f2bf(x0.w);
      a[4] = (short)f2bf(x1.x); a[5] = (short)f2bf(x1.y);
      a[6] = (short)f2bf(x1.z); a[7] = (short)f2bf(x1.w);
      af[i] = a;
    }
#pragma unroll
    for (int j = 0; j < 2; ++j) {
      bf8 bw = *(const bf8*)(Wgb + (size_t)(col0 + j * 16 + lr) * 512 + 256 + kk + lg * 8);
#pragma unroll
      for (int i = 0; i < 4; ++i)
        acc2[i][j] = __builtin_amdgcn_mfma_f32_16x16x32_bf16(af[i], bw, acc2[i][j], 0, 0, 0);
    }
  }

  // ---- epilogue: gate blend (P f32 from LDS, center bf16) ----
#pragma unroll
  for (int i = 0; i < 4; ++i)
#pragma unroll
    for (int j = 0; j < 2; ++j)
#pragma unroll
      for (int r = 0; r < 4; ++r) {
        const int lrow = i * 16 + lg * 4 + r;
        const int row = row0 + lrow;
        const int col = col0 + j * 16 + lr;
        float g = 1.f / (1.f + __expf(-acc2[i][j][r]));
        float pv = p_s[lrow][col];
        float cv = bf2f(centerBf[(size_t)row * 256 + col]);
        out[(size_t)row * 256 + col] = g * cv + (1.f - g) * pv;
      }
}

extern "C" void kernel_launch(void* const* d_in, const int* in_sizes, int n_in,
                              void* d_out, int out_size, void* d_ws, size_t ws_size,
                              hipStream_t stream) {
  const float* center = (const float*)d_in[0];
  const float* neigh  = (const float*)d_in[1];
  const float* nw     = (const float*)d_in[2];
  const int*   nm     = (const int*)d_in[3];
  const float* Wq     = (const float*)d_in[4];
  const float* Wk     = (const float*)d_in[5];
  const float* Wout   = (const float*)d_in[6];
  const float* Wgate  = (const float*)d_in[7];
  float* out = (float*)d_out;

  char* ws = (char*)d_ws;
  size_t off = 0;
  ushort* Mtb      = (ushort*)(ws + off); off += (size_t)512 * 256 * 2;        // 256 KB
  ushort* centerBf = (ushort*)(ws + off); off += (size_t)16384 * 256 * 2;      // 8 MB
  ushort* qMb      = (ushort*)(ws + off); off += (size_t)16384 * 512 * 2;      // 16 MB
  ushort* ctxb     = (ushort*)(ws + off); off += (size_t)16384 * 512 * 2;      // 16 MB
  ushort* Woutb    = (ushort*)(ws + off); off += (size_t)256 * 512 * 2;        // 256 KB
  ushort* Wgb      = (ushort*)(ws + off); off += (size_t)256 * 512 * 2;        // 256 KB

  // prologue: center cast + weight casts + Mt = Wq^T Wk (one launch)
  mhna_prologue<<<2816, 256, 0, stream>>>(center, centerBf, Wout, Wgate,
                                          Woutb, Wgb, Wq, Wk, Mtb);
  // qM = center @ Mt^T : [16384 x 512] bf16, K=256
  gemm_qM<<<256, 512, 0, stream>>>(centerBf, Mtb, qMb);
  // fused neighborhood attention (register-resident, mask-skipped loads)
  mhna_kC<<<16384, 256, 0, stream>>>(neigh, qMb, nw, nm, ctxb);
  // fused: P = ctx @ Wout^T ; gate = sigmoid([center,P] @ Wg^T) ; blend
  mhna_PG<<<256, 512, 0, stream>>>(ctxb, Woutb, centerBf, Wgb, out);
}